// Round 2
// baseline (963.512 us; speedup 1.0000x reference)
//
#include <hip/hip_runtime.h>
#include <hip/hip_bf16.h>

// EdgeProposer R8: occupancy 2->3 blocks/CU. R7 analysis: wall=456k cyc/SIMD,
// matrix busy=149k (33%) -> idle-bound at 2 waves/SIMD, LDS-limited
// (59392B -> 2 blocks). R8 cuts LDS to exactly 49152B:
//   - sIdx/tIdx alias into smem_u (read into regs pre-loop, +1 barrier)
//   - h2s eliminated: h2 written into acts cols 0..63 after C2 reads drain
// __launch_bounds__(256,3): 3 blocks/CU, reg cap ~341 unified (288 used).
// Also: cross-barrier prefetch of next step's seg0 bfr (5 loads, 20 VGPR,
// drained for free during seg2 MFMAs at the barrier's vmcnt(0)); T5
// setprio(1) around MFMA clusters (3 co-resident blocks = role diversity).

#define DD 512
#define K3 1536
#define ROWS 128
#define LDACT 328   // 320 + 8 pad (keep %8==0: 16B-aligned rows for b128)
#define BUFS 12288  // shorts per As2 buffer (3 seg * 8 rt * 64 lane * 8)

typedef short bf16x8 __attribute__((ext_vector_type(8)));
typedef float f32x4 __attribute__((ext_vector_type(4)));

__device__ inline float b2f(short s) {
    union { float f; unsigned u; } v;
    v.u = ((unsigned)(unsigned short)s) << 16;
    return v.f;
}
__device__ inline short f2b(float f) {   // RNE
    union { float fl; unsigned u; } v;
    v.fl = f;
    unsigned x = v.u;
    unsigned r = x + 0x7fffu + ((x >> 16) & 1u);
    return (short)(r >> 16);
}
__device__ inline short babsdiff(short a, short b) {
    union { float f; unsigned u; } v;
    v.f = b2f(a) - b2f(b);
    return (short)((v.u & 0x7fffffffu) >> 16);
}

// As2 fragment-major index (K-step 32): [seg][rt][lane][8] shorts
__device__ __forceinline__ int sidx32(int seg, int rt, int lane) {
    return ((seg * 8 + rt) * 64 + lane) * 8;
}

// cvt(abs-diff) + 6x b128 stores of one row's 16-k chunk into a buffer
__device__ __forceinline__ void writeStage(short* buf, int rtw, int lnw, int kcb,
                                           bf16x8 s0, bf16x8 s1,
                                           bf16x8 t0, bf16x8 t1) {
    bf16x8 a0, a1;
#pragma unroll
    for (int j = 0; j < 8; j++) {
        a0[j] = babsdiff(s0[j], t0[j]);
        a1[j] = babsdiff(s1[j], t1[j]);
    }
    int l0 = kcb * 16 + lnw, l1 = l0 + 16;
    *(bf16x8*)&buf[sidx32(0, rtw, l0)] = s0;
    *(bf16x8*)&buf[sidx32(0, rtw, l1)] = s1;
    *(bf16x8*)&buf[sidx32(1, rtw, l0)] = t0;
    *(bf16x8*)&buf[sidx32(1, rtw, l1)] = t1;
    *(bf16x8*)&buf[sidx32(2, rtw, l0)] = a0;
    *(bf16x8*)&buf[sidx32(2, rtw, l1)] = a1;
}

// f32 fallback path: load 16 f32 of src/tgt, cvt, stage (no prefetch split)
__device__ __forceinline__ void stage_f32(const float* bs, const float* bt,
                                          short* buf, int rtw, int lnw, int kcb) {
#pragma unroll
    for (int c = 0; c < 2; c++) {
        bf16x8 sb, tb, ab;
#pragma unroll
        for (int h = 0; h < 2; h++) {
            float4 s4 = ((const float4*)bs)[c * 2 + h];
            float4 t4 = ((const float4*)bt)[c * 2 + h];
            float ss[4] = {s4.x, s4.y, s4.z, s4.w};
            float tt[4] = {t4.x, t4.y, t4.z, t4.w};
#pragma unroll
            for (int e = 0; e < 4; e++) {
                int j = h * 4 + e;
                sb[j] = f2b(ss[e]);
                tb[j] = f2b(tt[e]);
                ab[j] = f2b(fabsf(ss[e] - tt[e]));
            }
        }
        int l16 = (kcb + c) * 16 + lnw;
        *(bf16x8*)&buf[sidx32(0, rtw, l16)] = sb;
        *(bf16x8*)&buf[sidx32(1, rtw, l16)] = tb;
        *(bf16x8*)&buf[sidx32(2, rtw, l16)] = ab;
    }
}

// ---- workspace layout (shorts) ----
#define WT_ELEMS (320 * 1536)
#define P2T_OFF WT_ELEMS
#define R2T_OFF (WT_ELEMS + 64 * 128)
#define PREP_TOT (WT_ELEMS + 2 * 64 * 128)
#define BEL_ELEMS (8192 * 512)
#define BEL_OFF PREP_TOT

// 8 elements per thread (bf16x8 stores; all region boundaries are %8==0)
__global__ void prep_kernel(const float* __restrict__ pw1,
                            const float* __restrict__ dw1,
                            const float* __restrict__ rw1,
                            const float* __restrict__ pw2,
                            const float* __restrict__ rw2,
                            const float* __restrict__ beliefs,
                            short* __restrict__ ws, int total8) {
    int i8 = blockIdx.x * 256 + threadIdx.x;
    if (i8 >= total8) return;
    int i = i8 * 8;
    bf16x8 o;
    if (i < WT_ELEMS) {
        int n = i / K3, k = i - n * K3;   // k..k+7 share n (K3 % 8 == 0)
        const float* src;
        int stride, off;
        if (n < 128)      { src = pw1; stride = 128; off = n; }
        else if (n < 192) { src = dw1; stride = 64;  off = n - 128; }
        else              { src = rw1; stride = 128; off = n - 192; }
#pragma unroll
        for (int j = 0; j < 8; j++) o[j] = f2b(src[(k + j) * stride + off]);
    } else if (i < R2T_OFF) {
        int jj = i - P2T_OFF;
        int n = jj >> 7, k = jj & 127;
#pragma unroll
        for (int j = 0; j < 8; j++) o[j] = f2b(pw2[(k + j) * 64 + n]);
    } else if (i < PREP_TOT) {
        int jj = i - R2T_OFF;
        int n = jj >> 7, k = jj & 127;
#pragma unroll
        for (int j = 0; j < 8; j++) o[j] = f2b(rw2[(k + j) * 64 + n]);
    } else {
        const float4* b4 = (const float4*)(beliefs + (i - BEL_OFF));
        float4 x = b4[0], y = b4[1];
        float v[8] = {x.x, x.y, x.z, x.w, y.x, y.y, y.z, y.w};
#pragma unroll
        for (int j = 0; j < 8; j++) o[j] = f2b(v[j]);
    }
    *(bf16x8*)&ws[i] = o;
}

// ---- main fused kernel: 128 pairs per block, 256 threads (4 waves) ----
template<bool BF>
__global__ __launch_bounds__(256, 3) void edge_main(
    const float* __restrict__ beliefs, const short* __restrict__ bel16,
    const int* __restrict__ src_idx, const int* __restrict__ tgt_idx,
    const float* __restrict__ pb1, const float* __restrict__ db1,
    const float* __restrict__ rb1,
    const float* __restrict__ pb2, const float* __restrict__ pw3,
    const float* __restrict__ pb3,
    const float* __restrict__ dw2, const float* __restrict__ db2,
    const float* __restrict__ rb2,
    const short* __restrict__ WT, const short* __restrict__ pw2T,
    const short* __restrict__ rw2T,
    float* __restrict__ out, int N)
{
    // single 48KB union: As2 double buffer (K-loop) / acts (epilogue) / idx
    __shared__ __align__(16) char smem_u[49152];

    short* As2 = (short*)smem_u;
    short (*acts)[LDACT] = (short (*)[LDACT])smem_u;
    int* sIdx = (int*)smem_u;          // alias: consumed into regs pre-loop
    int* tIdx = sIdx + ROWS;

    const int t = threadIdx.x;
    const int r0 = blockIdx.x * ROWS;
    const int w = t >> 6, lane = t & 63, q = lane >> 4, ln = lane & 15;

    if (t < ROWS) sIdx[t] = src_idx[r0 + t] * DD;
    else tIdx[t - ROWS] = tgt_idx[r0 + t - ROWS] * DD;
    __syncthreads();

    // staging role: thread pair (t, t^1) covers one row; kh = 16-k half of 32.
    const int rrow = t >> 1, kh = t & 1;
    const int rtw = rrow >> 4, lnw = rrow & 15;
    const int kcb = kh * 2;                 // base k-chunk (of 4 per step)
    const int srow = sIdx[rrow], trow = tIdx[rrow];
    __syncthreads();   // idx consumed before As2 overwrites the alias

    f32x4 acc[5][8];
#pragma unroll
    for (int ct = 0; ct < 5; ct++)
#pragma unroll
        for (int rt = 0; rt < 8; rt++) acc[ct][rt] = (f32x4)(0.f);

    // ---- prologue: seg0 bfr prefetch for step 0 + stage step 0 into buf0 ----
    bf16x8 bfr0[5];
#pragma unroll
    for (int ct = 0; ct < 5; ct++) {
        int col = w * 80 + ct * 16 + ln;
        bfr0[ct] = *(const bf16x8*)(WT + (size_t)col * K3 + q * 8);
    }
    if constexpr (BF) {
        const bf16x8* pS = (const bf16x8*)(bel16 + srow + kh * 16);
        const bf16x8* pT = (const bf16x8*)(bel16 + trow + kh * 16);
        writeStage(As2, rtw, lnw, kcb, pS[0], pS[1], pT[0], pT[1]);
    } else {
        stage_f32(beliefs + srow + kh * 16, beliefs + trow + kh * 16,
                  As2, rtw, lnw, kcb);
    }
    __syncthreads();

    // ---- main loop: 16 K-steps of 32, one barrier per step ----
    for (int step = 0; step < 16; ++step) {
        short* bufC = As2 + (step & 1) * BUFS;
        short* bufN = As2 + ((step & 1) ^ 1) * BUFS;
        const int k0 = step * 32;
        const bool pf = (step < 15);
        bf16x8 ns0, ns1, nt0, nt1;

#pragma unroll
        for (int seg = 0; seg < 3; seg++) {
            bf16x8 bfr[5];
            if (seg == 0) {
#pragma unroll
                for (int ct = 0; ct < 5; ct++) bfr[ct] = bfr0[ct];
            } else {
#pragma unroll
                for (int ct = 0; ct < 5; ct++) {
                    int col = w * 80 + ct * 16 + ln;
                    bfr[ct] = *(const bf16x8*)(WT + (size_t)col * K3 +
                                               seg * DD + k0 + q * 8);
                }
            }
            if (seg == 2) {
                // prefetch region: issued after this step's bfr loads so the
                // MFMA waits stay counted (vmcnt(N), N>0); everything here is
                // consumed pre-barrier (gathers) or post-barrier from regs
                // (bfr0), so the barrier's vmcnt(0) drain overlaps seg2 MFMAs.
                __builtin_amdgcn_sched_barrier(0);
                if (pf) {
                    if constexpr (BF) {
                        const bf16x8* pS = (const bf16x8*)(bel16 + srow + k0 + 32 + kh * 16);
                        const bf16x8* pT = (const bf16x8*)(bel16 + trow + k0 + 32 + kh * 16);
                        ns0 = pS[0]; ns1 = pS[1]; nt0 = pT[0]; nt1 = pT[1];
                    }
                    // next step's seg0 bfr -> regs across the barrier
#pragma unroll
                    for (int ct = 0; ct < 5; ct++) {
                        int col = w * 80 + ct * 16 + ln;
                        bfr0[ct] = *(const bf16x8*)(WT + (size_t)col * K3 +
                                                    k0 + 32 + q * 8);
                    }
                }
                __builtin_amdgcn_sched_barrier(0);
            }
            __builtin_amdgcn_s_setprio(1);
#pragma unroll
            for (int rt = 0; rt < 8; rt++) {
                bf16x8 af = *(const bf16x8*)&bufC[sidx32(seg, rt, lane)];
#pragma unroll
                for (int ct = 0; ct < 5; ct++)
                    acc[ct][rt] = __builtin_amdgcn_mfma_f32_16x16x32_bf16(
                        af, bfr[ct], acc[ct][rt], 0, 0, 0);
            }
            __builtin_amdgcn_s_setprio(0);
        }
        if constexpr (BF) {
            if (pf) writeStage(bufN, rtw, lnw, kcb, ns0, ns1, nt0, nt1);
        } else {
            if (pf) stage_f32(beliefs + srow + k0 + 32 + kh * 16,
                              beliefs + trow + k0 + 32 + kh * 16,
                              bufN, rtw, lnw, kcb);
        }
        __syncthreads();
    }

    // ---- epilogue: two 64-row halves; h2 lives in acts cols 0..63 ----
#pragma unroll
    for (int h = 0; h < 2; h++) {
        // phase B: bias + relu -> acts[64][320]. C/D: col=lane&15, row=q*4+reg.
#pragma unroll
        for (int ct = 0; ct < 5; ct++) {
            int col = w * 80 + ct * 16 + ln;
            float bias = (col < 128) ? pb1[col]
                       : (col < 192) ? db1[col - 128]
                                     : rb1[col - 192];
#pragma unroll
            for (int rt4 = 0; rt4 < 4; rt4++)
#pragma unroll
                for (int i = 0; i < 4; i++) {
                    int lrow = rt4 * 16 + q * 4 + i;
                    float v = acc[ct][h * 4 + rt4][i] + bias;
                    acts[lrow][col] = f2b(fmaxf(v, 0.f));
                }
        }
        __syncthreads();

        // C1: relations = relu1_r[64x128] @ rw2 + rb2 (reads acts 192..319)
        {
            f32x4 rc[4];
#pragma unroll
            for (int rt = 0; rt < 4; rt++) rc[rt] = (f32x4)(0.f);
#pragma unroll
            for (int ks = 0; ks < 4; ks++) {
                bf16x8 bfr = *(const bf16x8*)(rw2T + (w * 16 + ln) * 128 +
                                              ks * 32 + q * 8);
#pragma unroll
                for (int rt = 0; rt < 4; rt++) {
                    bf16x8 afr = *(const bf16x8*)&acts[rt * 16 + ln][192 + ks * 32 + q * 8];
                    rc[rt] = __builtin_amdgcn_mfma_f32_16x16x32_bf16(afr, bfr, rc[rt], 0, 0, 0);
                }
            }
            int col = w * 16 + ln;
            float bias = rb2[col];
            float* rel = out + 2 * (size_t)N;
#pragma unroll
            for (int rt = 0; rt < 4; rt++)
#pragma unroll
                for (int i = 0; i < 4; i++) {
                    int grow = r0 + h * 64 + rt * 16 + q * 4 + i;
                    rel[(size_t)grow * 64 + col] = rc[rt][i] + bias;
                }
        }

        // C2: pc = relu1_p[64x128] @ pw2 (reads acts 0..127) -> regs
        f32x4 pc[4];
        {
#pragma unroll
            for (int rt = 0; rt < 4; rt++) pc[rt] = (f32x4)(0.f);
#pragma unroll
            for (int ks = 0; ks < 4; ks++) {
                bf16x8 bfr = *(const bf16x8*)(pw2T + (w * 16 + ln) * 128 +
                                              ks * 32 + q * 8);
#pragma unroll
                for (int rt = 0; rt < 4; rt++) {
                    bf16x8 afr = *(const bf16x8*)&acts[rt * 16 + ln][0 + ks * 32 + q * 8];
                    pc[rt] = __builtin_amdgcn_mfma_f32_16x16x32_bf16(afr, bfr, pc[rt], 0, 0, 0);
                }
            }
        }
        __syncthreads();   // all C2 reads of acts cols 0..127 complete

        // write h2 = relu(pc + pb2) into acts cols 0..63 (now dead)
        {
            int col = w * 16 + ln;
            float bias = pb2[col];
#pragma unroll
            for (int rt = 0; rt < 4; rt++)
#pragma unroll
                for (int i = 0; i < 4; i++) {
                    int lrow = rt * 16 + q * 4 + i;
                    acts[lrow][col] = f2b(fmaxf(pc[rt][i] + bias, 0.f));
                }
        }
        __syncthreads();   // h2 visible

        // C3: probs (reads acts[t][0..63]); C4: directions (acts[.][128..191])
        if (t < 64) {
            float s = pb3[0];
#pragma unroll 8
            for (int k = 0; k < 64; k++) s += b2f(acts[t][k]) * pw3[k];
            float pr = 1.f / (1.f + __expf(-s));
            out[r0 + h * 64 + t] = pr;
        } else if (t < 128) {
            int lrow = t - 64;
            float s = db2[0];
#pragma unroll 8
            for (int k = 0; k < 64; k++) s += b2f(acts[lrow][128 + k]) * dw2[k];
            float dir = (1.f / (1.f + __expf(-s))) * 1.57079632679489662f;
            out[(size_t)N + r0 + h * 64 + lrow] = dir;
        }
        __syncthreads();   // protect acts before next half overwrites
    }
}

extern "C" void kernel_launch(void* const* d_in, const int* in_sizes, int n_in,
                              void* d_out, int out_size, void* d_ws, size_t ws_size,
                              hipStream_t stream) {
    const float* beliefs = (const float*)d_in[0];
    const int* src = (const int*)d_in[1];
    const int* tgt = (const int*)d_in[2];
    const float* pw1 = (const float*)d_in[3];
    const float* pb1 = (const float*)d_in[4];
    const float* pw2 = (const float*)d_in[5];
    const float* pb2 = (const float*)d_in[6];
    const float* pw3 = (const float*)d_in[7];
    const float* pb3 = (const float*)d_in[8];
    const float* dw1 = (const float*)d_in[9];
    const float* db1 = (const float*)d_in[10];
    const float* dw2 = (const float*)d_in[11];
    const float* db2 = (const float*)d_in[12];
    const float* rw1 = (const float*)d_in[13];
    const float* rb1 = (const float*)d_in[14];
    const float* rw2 = (const float*)d_in[15];
    const float* rb2 = (const float*)d_in[16];

    short* ws = (short*)d_ws;
    short* WT    = ws;
    short* pw2T  = ws + P2T_OFF;
    short* rw2T  = ws + R2T_OFF;
    short* bel16 = ws + BEL_OFF;
    const int N = in_sizes[1];

    const bool useBf = ws_size >= (size_t)(PREP_TOT + BEL_ELEMS) * sizeof(short);
    const int prepElems = useBf ? (PREP_TOT + BEL_ELEMS) : PREP_TOT;
    const int prep8 = prepElems / 8;

    prep_kernel<<<(prep8 + 255) / 256, 256, 0, stream>>>(
        pw1, dw1, rw1, pw2, rw2, beliefs, ws, prep8);

    if (useBf)
        edge_main<true><<<N / ROWS, 256, 0, stream>>>(
            beliefs, bel16, src, tgt, pb1, db1, rb1, pb2, pw3, pb3,
            dw2, db2, rb2, WT, pw2T, rw2T, (float*)d_out, N);
    else
        edge_main<false><<<N / ROWS, 256, 0, stream>>>(
            beliefs, bel16, src, tgt, pb1, db1, rb1, pb2, pw3, pb3,
            dw2, db2, rb2, WT, pw2T, rw2T, (float*)d_out, N);
}

// Round 3
// 323.605 us; speedup vs baseline: 2.9774x; 2.9774x over previous
//
#include <hip/hip_runtime.h>
#include <hip/hip_bf16.h>

// EdgeProposer R9. R8 post-mortem: launch_bounds(256,3) reg-cap -> acc spill
// (WRITE 33MB->2.2GB) -> 963us. Occupancy >2 waves/SIMD is structurally
// unreachable (160-reg accumulator). R9 = R7 structure + distance-2 DMA
// prefetch (global_load_lds) of the s/t gather panels into a 3-slot LDS ring,
// |s-t| computed in-step from LDS into an 8KB seg2 scratch. Raw s_barriers
// with counted waits: mid-step B = lgkmcnt(0) (seg2 visibility), end-step
// D = vmcnt(4)+lgkmcnt(0) (DMA never drained to 0 in steady state; budget
// ~1.5 steps covers L3/HBM gather latency). No launch_bounds cap beyond
// (256,2); no cross-barrier register prefetch (R8 trap).

#define DD 512
#define K3 1536
#define ROWS 128
#define LDACT 328      // 320 + 8 pad, rows 16B-aligned
#define SLOT 8192      // shorts per ring slot: s[8rt][64][8] + t[8rt][64][8]
#define SEG2 24576     // shorts: seg2 scratch after 3 ring slots
// LDS total = (24576 + 4096) shorts = 57344 B

typedef short bf16x8 __attribute__((ext_vector_type(8)));
typedef float f32x4 __attribute__((ext_vector_type(4)));

__device__ inline float b2f(short s) {
    union { float f; unsigned u; } v;
    v.u = ((unsigned)(unsigned short)s) << 16;
    return v.f;
}
__device__ inline short f2b(float f) {   // RNE
    union { float fl; unsigned u; } v;
    v.fl = f;
    unsigned x = v.u;
    unsigned r = x + 0x7fffu + ((x >> 16) & 1u);
    return (short)(r >> 16);
}
__device__ inline short babsdiff(short a, short b) {
    union { float f; unsigned u; } v;
    v.f = b2f(a) - b2f(b);
    return (short)((v.u & 0x7fffffffu) >> 16);
}

__device__ __forceinline__ void gload_lds16(const short* g, short* l) {
    __builtin_amdgcn_global_load_lds(
        (const __attribute__((address_space(1))) void*)g,
        (__attribute__((address_space(3))) void*)l, 16, 0, 0);
}

// f32 fallback: load 16 f32 of src/tgt, cvt to bf16, write s/t into ring slot
__device__ __forceinline__ void stageF32(const float* bs, const float* bt,
                                         short* slot, int oA) {
    bf16x8 s0, s1, t0, t1;
#pragma unroll
    for (int c = 0; c < 2; c++) {
#pragma unroll
        for (int h = 0; h < 2; h++) {
            float4 s4 = ((const float4*)bs)[c * 2 + h];
            float4 t4 = ((const float4*)bt)[c * 2 + h];
            float ss[4] = {s4.x, s4.y, s4.z, s4.w};
            float tt[4] = {t4.x, t4.y, t4.z, t4.w};
#pragma unroll
            for (int e = 0; e < 4; e++) {
                int j = h * 4 + e;
                if (c == 0) { s0[j] = f2b(ss[e]); t0[j] = f2b(tt[e]); }
                else        { s1[j] = f2b(ss[e]); t1[j] = f2b(tt[e]); }
            }
        }
    }
    *(bf16x8*)&slot[oA] = s0;
    *(bf16x8*)&slot[oA + 128] = s1;
    *(bf16x8*)&slot[4096 + oA] = t0;
    *(bf16x8*)&slot[4096 + oA + 128] = t1;
}

// ---- workspace layout (shorts) ----
#define WT_ELEMS (320 * 1536)
#define P2T_OFF WT_ELEMS
#define R2T_OFF (WT_ELEMS + 64 * 128)
#define PREP_TOT (WT_ELEMS + 2 * 64 * 128)
#define BEL_ELEMS (8192 * 512)
#define BEL_OFF PREP_TOT

// 8 elements per thread (bf16x8 stores; all region boundaries are %8==0)
__global__ void prep_kernel(const float* __restrict__ pw1,
                            const float* __restrict__ dw1,
                            const float* __restrict__ rw1,
                            const float* __restrict__ pw2,
                            const float* __restrict__ rw2,
                            const float* __restrict__ beliefs,
                            short* __restrict__ ws, int total8) {
    int i8 = blockIdx.x * 256 + threadIdx.x;
    if (i8 >= total8) return;
    int i = i8 * 8;
    bf16x8 o;
    if (i < WT_ELEMS) {
        int n = i / K3, k = i - n * K3;   // k..k+7 share n (K3 % 8 == 0)
        const float* src;
        int stride, off;
        if (n < 128)      { src = pw1; stride = 128; off = n; }
        else if (n < 192) { src = dw1; stride = 64;  off = n - 128; }
        else              { src = rw1; stride = 128; off = n - 192; }
#pragma unroll
        for (int j = 0; j < 8; j++) o[j] = f2b(src[(k + j) * stride + off]);
    } else if (i < R2T_OFF) {
        int jj = i - P2T_OFF;
        int n = jj >> 7, k = jj & 127;
#pragma unroll
        for (int j = 0; j < 8; j++) o[j] = f2b(pw2[(k + j) * 64 + n]);
    } else if (i < PREP_TOT) {
        int jj = i - R2T_OFF;
        int n = jj >> 7, k = jj & 127;
#pragma unroll
        for (int j = 0; j < 8; j++) o[j] = f2b(rw2[(k + j) * 64 + n]);
    } else {
        const float4* b4 = (const float4*)(beliefs + (i - BEL_OFF));
        float4 x = b4[0], y = b4[1];
        float v[8] = {x.x, x.y, x.z, x.w, y.x, y.y, y.z, y.w};
#pragma unroll
        for (int j = 0; j < 8; j++) o[j] = f2b(v[j]);
    }
    *(bf16x8*)&ws[i] = o;
}

// ---- main fused kernel: 128 pairs per block, 256 threads (4 waves) ----
template<bool BF>
__global__ __launch_bounds__(256, 2) void edge_main(
    const float* __restrict__ beliefs, const short* __restrict__ bel16,
    const int* __restrict__ src_idx, const int* __restrict__ tgt_idx,
    const float* __restrict__ pb1, const float* __restrict__ db1,
    const float* __restrict__ rb1,
    const float* __restrict__ pb2, const float* __restrict__ pw3,
    const float* __restrict__ pb3,
    const float* __restrict__ dw2, const float* __restrict__ db2,
    const float* __restrict__ rb2,
    const short* __restrict__ WT, const short* __restrict__ pw2T,
    const short* __restrict__ rw2T,
    float* __restrict__ out, int N)
{
    // union: K-loop ring (48KB) + seg2 scratch (8KB) / epilogue acts / idx
    __shared__ __align__(16) char smem_u[57344];
    short* sm = (short*)smem_u;
    short (*acts)[LDACT] = (short (*)[LDACT])smem_u;
    int* sIdx = (int*)smem_u;          // alias: consumed into regs pre-loop
    int* tIdx = sIdx + ROWS;

    const int t = threadIdx.x;
    const int r0 = blockIdx.x * ROWS;
    const int w = t >> 6, lane = t & 63, q = lane >> 4, ln = lane & 15;

    if (t < ROWS) sIdx[t] = src_idx[r0 + t] * DD;
    else tIdx[t - ROWS] = tgt_idx[r0 + t - ROWS] * DD;
    __syncthreads();

    // staging role: thread pair (t, t^1) covers one row; kh = 16-k half of 32.
    const int rrow = t >> 1, kh = t & 1;
    const int rtw = rrow >> 4, lnw = rrow & 15;
    const int l0 = kh * 32 + lnw;
    const int oA = rtw * 512 + l0 * 8;   // A-phase base offset within a slot

    // per-lane DMA sources (BF) or staging rows (f32) -- wave w DMAs rt 2w,2w+1
    const short *pS0 = nullptr, *pS1 = nullptr, *pT0 = nullptr, *pT1 = nullptr;
    int srowF = 0, trowF = 0;
    if constexpr (BF) {
        pS0 = bel16 + sIdx[(2 * w) * 16 + ln] + q * 8;
        pS1 = bel16 + sIdx[(2 * w + 1) * 16 + ln] + q * 8;
        pT0 = bel16 + tIdx[(2 * w) * 16 + ln] + q * 8;
        pT1 = bel16 + tIdx[(2 * w + 1) * 16 + ln] + q * 8;
    } else {
        srowF = sIdx[rrow]; trowF = tIdx[rrow];
    }
    __syncthreads();   // idx consumed before ring slot 0 overwrites the alias

    f32x4 acc[5][8];
#pragma unroll
    for (int ct = 0; ct < 5; ct++)
#pragma unroll
        for (int rt = 0; rt < 8; rt++) acc[ct][rt] = (f32x4)(0.f);

    // ---- prologue: stage k=0 -> ring0, k=32 -> ring1 ----
    if constexpr (BF) {
#pragma unroll
        for (int u = 0; u < 2; u++) {
            short* d = sm + u * SLOT;
            gload_lds16(pS0 + u * 32, &d[(2 * w) * 512]);
            gload_lds16(pS1 + u * 32, &d[(2 * w + 1) * 512]);
            gload_lds16(pT0 + u * 32, &d[4096 + (2 * w) * 512]);
            gload_lds16(pT1 + u * 32, &d[4096 + (2 * w + 1) * 512]);
        }
        pS0 += 64; pS1 += 64; pT0 += 64; pT1 += 64;   // -> k=64 (set for step 0's issue)
    } else {
        stageF32(beliefs + srowF + kh * 16, beliefs + trowF + kh * 16, sm, oA);
        stageF32(beliefs + srowF + 32 + kh * 16, beliefs + trowF + 32 + kh * 16,
                 sm + SLOT, oA);
    }
    __syncthreads();   // full drain once at startup

    // ---- main loop: 16 K-steps of 32 ----
    int cur = 0;
    for (int step = 0; step < 16; ++step) {
        const int k0 = step * 32;
        int nxt2 = cur + 2; if (nxt2 >= 3) nxt2 -= 3;
        short* slotC = sm + cur * SLOT;

        // seg0 bfr issue (consumed ~100cy later, after stage)
        bf16x8 b0[5];
#pragma unroll
        for (int ct = 0; ct < 5; ct++)
            b0[ct] = *(const bf16x8*)(WT + (size_t)(w * 80 + ct * 16 + ln) * K3 +
                                      k0 + q * 8);

        // A: seg2 stage -- own-wave rows, data guaranteed by pre-D wait of t-1
        {
            bf16x8 s0 = *(const bf16x8*)&slotC[oA];
            bf16x8 s1 = *(const bf16x8*)&slotC[oA + 128];
            bf16x8 t0 = *(const bf16x8*)&slotC[4096 + oA];
            bf16x8 t1 = *(const bf16x8*)&slotC[4096 + oA + 128];
            bf16x8 a0, a1;
#pragma unroll
            for (int j = 0; j < 8; j++) {
                a0[j] = babsdiff(s0[j], t0[j]);
                a1[j] = babsdiff(s1[j], t1[j]);
            }
            *(bf16x8*)&sm[SEG2 + oA] = a0;
            *(bf16x8*)&sm[SEG2 + oA + 128] = a1;
        }

        // seg0 MFMAs (af = ring.s, stable since D(t-1))
        __builtin_amdgcn_s_setprio(1);
#pragma unroll
        for (int rt = 0; rt < 8; rt++) {
            bf16x8 af = *(const bf16x8*)&slotC[rt * 512 + lane * 8];
#pragma unroll
            for (int ct = 0; ct < 5; ct++)
                acc[ct][rt] = __builtin_amdgcn_mfma_f32_16x16x32_bf16(
                    af, b0[ct], acc[ct][rt], 0, 0, 0);
        }
        __builtin_amdgcn_s_setprio(0);

        // seg1 bfr issue (hidden under seg0 MFMAs + barrier)
        bf16x8 b1[5];
#pragma unroll
        for (int ct = 0; ct < 5; ct++)
            b1[ct] = *(const bf16x8*)(WT + (size_t)(w * 80 + ct * 16 + ln) * K3 +
                                      DD + k0 + q * 8);

        // B: seg2 scratch visible to all waves (lgkm only -- no vmcnt drain)
        asm volatile("s_waitcnt lgkmcnt(0)" ::: "memory");
        __builtin_amdgcn_s_barrier();
        __builtin_amdgcn_sched_barrier(0);

        // seg1 MFMAs (af = ring.t)
        __builtin_amdgcn_s_setprio(1);
#pragma unroll
        for (int rt = 0; rt < 8; rt++) {
            bf16x8 af = *(const bf16x8*)&slotC[4096 + rt * 512 + lane * 8];
#pragma unroll
            for (int ct = 0; ct < 5; ct++)
                acc[ct][rt] = __builtin_amdgcn_mfma_f32_16x16x32_bf16(
                    af, b1[ct], acc[ct][rt], 0, 0, 0);
        }
        __builtin_amdgcn_s_setprio(0);

        // seg2 bfr issue
        bf16x8 b2[5];
#pragma unroll
        for (int ct = 0; ct < 5; ct++)
            b2[ct] = *(const bf16x8*)(WT + (size_t)(w * 80 + ct * 16 + ln) * K3 +
                                      2 * DD + k0 + q * 8);

        // distance-2 prefetch for step+2 (issued AFTER all this step's bfr:
        // their counted waits never include the slow DMA)
        if (step < 14) {
            if constexpr (BF) {
                short* d = sm + nxt2 * SLOT;
                gload_lds16(pS0, &d[(2 * w) * 512]);
                gload_lds16(pS1, &d[(2 * w + 1) * 512]);
                gload_lds16(pT0, &d[4096 + (2 * w) * 512]);
                gload_lds16(pT1, &d[4096 + (2 * w + 1) * 512]);
                pS0 += 32; pS1 += 32; pT0 += 32; pT1 += 32;
            } else {
                stageF32(beliefs + srowF + k0 + 64 + kh * 16,
                         beliefs + trowF + k0 + 64 + kh * 16,
                         sm + nxt2 * SLOT, oA);
            }
        }

        // seg2 MFMAs (af = seg2 scratch, visible since B)
        __builtin_amdgcn_s_setprio(1);
#pragma unroll
        for (int rt = 0; rt < 8; rt++) {
            bf16x8 af = *(const bf16x8*)&sm[SEG2 + rt * 512 + lane * 8];
#pragma unroll
            for (int ct = 0; ct < 5; ct++)
                acc[ct][rt] = __builtin_amdgcn_mfma_f32_16x16x32_bf16(
                    af, b2[ct], acc[ct][rt], 0, 0, 0);
        }
        __builtin_amdgcn_s_setprio(0);

        // D: own set(t+1) complete (counted, newest 4 = set(t+2) may fly);
        // barrier makes it cross-wave. Never vmcnt(0) until the ring drains.
        if (step < 14) asm volatile("s_waitcnt vmcnt(4) lgkmcnt(0)" ::: "memory");
        else           asm volatile("s_waitcnt vmcnt(0) lgkmcnt(0)" ::: "memory");
        __builtin_amdgcn_s_barrier();
        __builtin_amdgcn_sched_barrier(0);

        cur++; if (cur == 3) cur = 0;
    }
    __syncthreads();   // safety drain before acts aliasing

    // ---- epilogue: two 64-row halves; h2 lives in acts cols 0..63 ----
#pragma unroll
    for (int h = 0; h < 2; h++) {
        // phase B: bias + relu -> acts[64][320]. C/D: col=lane&15, row=q*4+reg.
#pragma unroll
        for (int ct = 0; ct < 5; ct++) {
            int col = w * 80 + ct * 16 + ln;
            float bias = (col < 128) ? pb1[col]
                       : (col < 192) ? db1[col - 128]
                                     : rb1[col - 192];
#pragma unroll
            for (int rt4 = 0; rt4 < 4; rt4++)
#pragma unroll
                for (int i = 0; i < 4; i++) {
                    int lrow = rt4 * 16 + q * 4 + i;
                    float v = acc[ct][h * 4 + rt4][i] + bias;
                    acts[lrow][col] = f2b(fmaxf(v, 0.f));
                }
        }
        __syncthreads();

        // C1: relations = relu1_r[64x128] @ rw2 + rb2 (reads acts 192..319)
        {
            f32x4 rc[4];
#pragma unroll
            for (int rt = 0; rt < 4; rt++) rc[rt] = (f32x4)(0.f);
#pragma unroll
            for (int ks = 0; ks < 4; ks++) {
                bf16x8 bfr = *(const bf16x8*)(rw2T + (w * 16 + ln) * 128 +
                                              ks * 32 + q * 8);
#pragma unroll
                for (int rt = 0; rt < 4; rt++) {
                    bf16x8 afr = *(const bf16x8*)&acts[rt * 16 + ln][192 + ks * 32 + q * 8];
                    rc[rt] = __builtin_amdgcn_mfma_f32_16x16x32_bf16(afr, bfr, rc[rt], 0, 0, 0);
                }
            }
            int col = w * 16 + ln;
            float bias = rb2[col];
            float* rel = out + 2 * (size_t)N;
#pragma unroll
            for (int rt = 0; rt < 4; rt++)
#pragma unroll
                for (int i = 0; i < 4; i++) {
                    int grow = r0 + h * 64 + rt * 16 + q * 4 + i;
                    rel[(size_t)grow * 64 + col] = rc[rt][i] + bias;
                }
        }

        // C2: pc = relu1_p[64x128] @ pw2 (reads acts 0..127) -> regs
        f32x4 pc[4];
        {
#pragma unroll
            for (int rt = 0; rt < 4; rt++) pc[rt] = (f32x4)(0.f);
#pragma unroll
            for (int ks = 0; ks < 4; ks++) {
                bf16x8 bfr = *(const bf16x8*)(pw2T + (w * 16 + ln) * 128 +
                                              ks * 32 + q * 8);
#pragma unroll
                for (int rt = 0; rt < 4; rt++) {
                    bf16x8 afr = *(const bf16x8*)&acts[rt * 16 + ln][0 + ks * 32 + q * 8];
                    pc[rt] = __builtin_amdgcn_mfma_f32_16x16x32_bf16(afr, bfr, pc[rt], 0, 0, 0);
                }
            }
        }
        __syncthreads();   // all C2 reads of acts cols 0..127 complete

        // write h2 = relu(pc + pb2) into acts cols 0..63 (now dead)
        {
            int col = w * 16 + ln;
            float bias = pb2[col];
#pragma unroll
            for (int rt = 0; rt < 4; rt++)
#pragma unroll
                for (int i = 0; i < 4; i++) {
                    int lrow = rt * 16 + q * 4 + i;
                    acts[lrow][col] = f2b(fmaxf(pc[rt][i] + bias, 0.f));
                }
        }
        __syncthreads();   // h2 visible

        // C3: probs (reads acts[t][0..63]); C4: directions (acts[.][128..191])
        if (t < 64) {
            float s = pb3[0];
#pragma unroll 8
            for (int k = 0; k < 64; k++) s += b2f(acts[t][k]) * pw3[k];
            float pr = 1.f / (1.f + __expf(-s));
            out[r0 + h * 64 + t] = pr;
        } else if (t < 128) {
            int lrow = t - 64;
            float s = db2[0];
#pragma unroll 8
            for (int k = 0; k < 64; k++) s += b2f(acts[lrow][128 + k]) * dw2[k];
            float dir = (1.f / (1.f + __expf(-s))) * 1.57079632679489662f;
            out[(size_t)N + r0 + h * 64 + lrow] = dir;
        }
        __syncthreads();   // protect acts before next half overwrites
    }
}

extern "C" void kernel_launch(void* const* d_in, const int* in_sizes, int n_in,
                              void* d_out, int out_size, void* d_ws, size_t ws_size,
                              hipStream_t stream) {
    const float* beliefs = (const float*)d_in[0];
    const int* src = (const int*)d_in[1];
    const int* tgt = (const int*)d_in[2];
    const float* pw1 = (const float*)d_in[3];
    const float* pb1 = (const float*)d_in[4];
    const float* pw2 = (const float*)d_in[5];
    const float* pb2 = (const float*)d_in[6];
    const float* pw3 = (const float*)d_in[7];
    const float* pb3 = (const float*)d_in[8];
    const float* dw1 = (const float*)d_in[9];
    const float* db1 = (const float*)d_in[10];
    const float* dw2 = (const float*)d_in[11];
    const float* db2 = (const float*)d_in[12];
    const float* rw1 = (const float*)d_in[13];
    const float* rb1 = (const float*)d_in[14];
    const float* rw2 = (const float*)d_in[15];
    const float* rb2 = (const float*)d_in[16];

    short* ws = (short*)d_ws;
    short* WT    = ws;
    short* pw2T  = ws + P2T_OFF;
    short* rw2T  = ws + R2T_OFF;
    short* bel16 = ws + BEL_OFF;
    const int N = in_sizes[1];

    const bool useBf = ws_size >= (size_t)(PREP_TOT + BEL_ELEMS) * sizeof(short);
    const int prepElems = useBf ? (PREP_TOT + BEL_ELEMS) : PREP_TOT;
    const int prep8 = prepElems / 8;

    prep_kernel<<<(prep8 + 255) / 256, 256, 0, stream>>>(
        pw1, dw1, rw1, pw2, rw2, beliefs, ws, prep8);

    if (useBf)
        edge_main<true><<<N / ROWS, 256, 0, stream>>>(
            beliefs, bel16, src, tgt, pb1, db1, rb1, pb2, pw3, pb3,
            dw2, db2, rb2, WT, pw2T, rw2T, (float*)d_out, N);
    else
        edge_main<false><<<N / ROWS, 256, 0, stream>>>(
            beliefs, bel16, src, tgt, pb1, db1, rb1, pb2, pw3, pb3,
            dw2, db2, rb2, WT, pw2T, rw2T, (float*)d_out, N);
}

// Round 4
// 266.394 us; speedup vs baseline: 3.6169x; 1.2148x over previous
//
#include <hip/hip_runtime.h>
#include <hip/hip_bf16.h>

// EdgeProposer R10 = R7 schedule + R8's two safe deltas, WITHOUT the reg cap.
// R8 post-mortem: launch_bounds(256,3) forced alloc under the 160-reg acc ->
// spill (WRITE 33MB->2.2GB). R9 post-mortem: hand barriers/waitcnt + DMA ring
// lost to the compiler's own pipeline (MfmaUtil 30->21) and "memory" clobbers
// spilled ~8 regs/step. R10 keeps the compiler-scheduled single-barrier step:
//   - LDS exactly 49152B (idx aliased into union; h2 -> dead acts cols 0..63):
//     IF the unified reg pool allows 3 blocks/CU, occupancy 22->33% for free.
//   - cross-barrier bfr0[5] prefetch (+20 VGPR): removes the only post-barrier
//     global-latency segment (~200-400cy L2 hit on WT) from the serial path.
//   - T5 setprio(1) around MFMA clusters.
// Tripwire: WRITE_SIZE must stay ~33.8MB; a jump = spill -> drop prefetch.

#define DD 512
#define K3 1536
#define ROWS 128
#define LDACT 328   // 320 + 8 pad (keep %8==0: 16B-aligned rows for b128)
#define BUFS 12288  // shorts per As2 buffer (3 seg * 8 rt * 64 lane * 8)

typedef short bf16x8 __attribute__((ext_vector_type(8)));
typedef float f32x4 __attribute__((ext_vector_type(4)));

__device__ inline float b2f(short s) {
    union { float f; unsigned u; } v;
    v.u = ((unsigned)(unsigned short)s) << 16;
    return v.f;
}
__device__ inline short f2b(float f) {   // RNE
    union { float fl; unsigned u; } v;
    v.fl = f;
    unsigned x = v.u;
    unsigned r = x + 0x7fffu + ((x >> 16) & 1u);
    return (short)(r >> 16);
}
__device__ inline short babsdiff(short a, short b) {
    union { float f; unsigned u; } v;
    v.f = b2f(a) - b2f(b);
    return (short)((v.u & 0x7fffffffu) >> 16);
}

// As2 fragment-major index (K-step 32): [seg][rt][lane][8] shorts
__device__ __forceinline__ int sidx32(int seg, int rt, int lane) {
    return ((seg * 8 + rt) * 64 + lane) * 8;
}

// cvt(abs-diff) + 6x b128 stores of one row's 16-k chunk into a buffer
__device__ __forceinline__ void writeStage(short* buf, int rtw, int lnw, int kcb,
                                           bf16x8 s0, bf16x8 s1,
                                           bf16x8 t0, bf16x8 t1) {
    bf16x8 a0, a1;
#pragma unroll
    for (int j = 0; j < 8; j++) {
        a0[j] = babsdiff(s0[j], t0[j]);
        a1[j] = babsdiff(s1[j], t1[j]);
    }
    int l0 = kcb * 16 + lnw, l1 = l0 + 16;
    *(bf16x8*)&buf[sidx32(0, rtw, l0)] = s0;
    *(bf16x8*)&buf[sidx32(0, rtw, l1)] = s1;
    *(bf16x8*)&buf[sidx32(1, rtw, l0)] = t0;
    *(bf16x8*)&buf[sidx32(1, rtw, l1)] = t1;
    *(bf16x8*)&buf[sidx32(2, rtw, l0)] = a0;
    *(bf16x8*)&buf[sidx32(2, rtw, l1)] = a1;
}

// f32 fallback path: load 16 f32 of src/tgt, cvt, stage (no prefetch split)
__device__ __forceinline__ void stage_f32(const float* bs, const float* bt,
                                          short* buf, int rtw, int lnw, int kcb) {
#pragma unroll
    for (int c = 0; c < 2; c++) {
        bf16x8 sb, tb, ab;
#pragma unroll
        for (int h = 0; h < 2; h++) {
            float4 s4 = ((const float4*)bs)[c * 2 + h];
            float4 t4 = ((const float4*)bt)[c * 2 + h];
            float ss[4] = {s4.x, s4.y, s4.z, s4.w};
            float tt[4] = {t4.x, t4.y, t4.z, t4.w};
#pragma unroll
            for (int e = 0; e < 4; e++) {
                int j = h * 4 + e;
                sb[j] = f2b(ss[e]);
                tb[j] = f2b(tt[e]);
                ab[j] = f2b(fabsf(ss[e] - tt[e]));
            }
        }
        int l16 = (kcb + c) * 16 + lnw;
        *(bf16x8*)&buf[sidx32(0, rtw, l16)] = sb;
        *(bf16x8*)&buf[sidx32(1, rtw, l16)] = tb;
        *(bf16x8*)&buf[sidx32(2, rtw, l16)] = ab;
    }
}

// ---- workspace layout (shorts) ----
#define WT_ELEMS (320 * 1536)
#define P2T_OFF WT_ELEMS
#define R2T_OFF (WT_ELEMS + 64 * 128)
#define PREP_TOT (WT_ELEMS + 2 * 64 * 128)
#define BEL_ELEMS (8192 * 512)
#define BEL_OFF PREP_TOT

// 8 elements per thread (bf16x8 stores; all region boundaries are %8==0)
__global__ void prep_kernel(const float* __restrict__ pw1,
                            const float* __restrict__ dw1,
                            const float* __restrict__ rw1,
                            const float* __restrict__ pw2,
                            const float* __restrict__ rw2,
                            const float* __restrict__ beliefs,
                            short* __restrict__ ws, int total8) {
    int i8 = blockIdx.x * 256 + threadIdx.x;
    if (i8 >= total8) return;
    int i = i8 * 8;
    bf16x8 o;
    if (i < WT_ELEMS) {
        int n = i / K3, k = i - n * K3;   // k..k+7 share n (K3 % 8 == 0)
        const float* src;
        int stride, off;
        if (n < 128)      { src = pw1; stride = 128; off = n; }
        else if (n < 192) { src = dw1; stride = 64;  off = n - 128; }
        else              { src = rw1; stride = 128; off = n - 192; }
#pragma unroll
        for (int j = 0; j < 8; j++) o[j] = f2b(src[(k + j) * stride + off]);
    } else if (i < R2T_OFF) {
        int jj = i - P2T_OFF;
        int n = jj >> 7, k = jj & 127;
#pragma unroll
        for (int j = 0; j < 8; j++) o[j] = f2b(pw2[(k + j) * 64 + n]);
    } else if (i < PREP_TOT) {
        int jj = i - R2T_OFF;
        int n = jj >> 7, k = jj & 127;
#pragma unroll
        for (int j = 0; j < 8; j++) o[j] = f2b(rw2[(k + j) * 64 + n]);
    } else {
        const float4* b4 = (const float4*)(beliefs + (i - BEL_OFF));
        float4 x = b4[0], y = b4[1];
        float v[8] = {x.x, x.y, x.z, x.w, y.x, y.y, y.z, y.w};
#pragma unroll
        for (int j = 0; j < 8; j++) o[j] = f2b(v[j]);
    }
    *(bf16x8*)&ws[i] = o;
}

// ---- main fused kernel: 128 pairs per block, 256 threads (4 waves) ----
template<bool BF>
__global__ __launch_bounds__(256, 2) void edge_main(
    const float* __restrict__ beliefs, const short* __restrict__ bel16,
    const int* __restrict__ src_idx, const int* __restrict__ tgt_idx,
    const float* __restrict__ pb1, const float* __restrict__ db1,
    const float* __restrict__ rb1,
    const float* __restrict__ pb2, const float* __restrict__ pw3,
    const float* __restrict__ pb3,
    const float* __restrict__ dw2, const float* __restrict__ db2,
    const float* __restrict__ rb2,
    const short* __restrict__ WT, const short* __restrict__ pw2T,
    const short* __restrict__ rw2T,
    float* __restrict__ out, int N)
{
    // single 48KB union: As2 double buffer (K-loop) / acts (epilogue) / idx
    __shared__ __align__(16) char smem_u[49152];

    short* As2 = (short*)smem_u;
    short (*acts)[LDACT] = (short (*)[LDACT])smem_u;
    int* sIdx = (int*)smem_u;          // alias: consumed into regs pre-loop
    int* tIdx = sIdx + ROWS;

    const int t = threadIdx.x;
    const int r0 = blockIdx.x * ROWS;
    const int w = t >> 6, lane = t & 63, q = lane >> 4, ln = lane & 15;

    if (t < ROWS) sIdx[t] = src_idx[r0 + t] * DD;
    else tIdx[t - ROWS] = tgt_idx[r0 + t - ROWS] * DD;
    __syncthreads();

    // staging role: thread pair (t, t^1) covers one row; kh = 16-k half of 32.
    const int rrow = t >> 1, kh = t & 1;
    const int rtw = rrow >> 4, lnw = rrow & 15;
    const int kcb = kh * 2;                 // base k-chunk (of 4 per step)
    const int srow = sIdx[rrow], trow = tIdx[rrow];
    __syncthreads();   // idx consumed before As2 overwrites the alias

    f32x4 acc[5][8];
#pragma unroll
    for (int ct = 0; ct < 5; ct++)
#pragma unroll
        for (int rt = 0; rt < 8; rt++) acc[ct][rt] = (f32x4)(0.f);

    // ---- prologue: seg0 bfr prefetch for step 0 + stage step 0 into buf0 ----
    bf16x8 bfr0[5];
#pragma unroll
    for (int ct = 0; ct < 5; ct++) {
        int col = w * 80 + ct * 16 + ln;
        bfr0[ct] = *(const bf16x8*)(WT + (size_t)col * K3 + q * 8);
    }
    if constexpr (BF) {
        const bf16x8* pS = (const bf16x8*)(bel16 + srow + kh * 16);
        const bf16x8* pT = (const bf16x8*)(bel16 + trow + kh * 16);
        writeStage(As2, rtw, lnw, kcb, pS[0], pS[1], pT[0], pT[1]);
    } else {
        stage_f32(beliefs + srow + kh * 16, beliefs + trow + kh * 16,
                  As2, rtw, lnw, kcb);
    }
    __syncthreads();

    // ---- main loop: 16 K-steps of 32, one barrier per step ----
    for (int step = 0; step < 16; ++step) {
        short* bufC = As2 + (step & 1) * BUFS;
        short* bufN = As2 + ((step & 1) ^ 1) * BUFS;
        const int k0 = step * 32;
        const bool pf = (step < 15);
        bf16x8 ns0, ns1, nt0, nt1;

#pragma unroll
        for (int seg = 0; seg < 3; seg++) {
            bf16x8 bfr[5];
            if (seg == 0) {
#pragma unroll
                for (int ct = 0; ct < 5; ct++) bfr[ct] = bfr0[ct];
            } else {
#pragma unroll
                for (int ct = 0; ct < 5; ct++) {
                    int col = w * 80 + ct * 16 + ln;
                    bfr[ct] = *(const bf16x8*)(WT + (size_t)col * K3 +
                                               seg * DD + k0 + q * 8);
                }
            }
            if (seg == 2) {
                // prefetch region: issued after this step's bfr loads so the
                // MFMA waits stay counted (vmcnt(N), N>0); everything here is
                // consumed pre-barrier (gathers) or post-barrier from regs
                // (bfr0), so the barrier's vmcnt(0) drain overlaps seg2 MFMAs.
                __builtin_amdgcn_sched_barrier(0);
                if (pf) {
                    if constexpr (BF) {
                        const bf16x8* pS = (const bf16x8*)(bel16 + srow + k0 + 32 + kh * 16);
                        const bf16x8* pT = (const bf16x8*)(bel16 + trow + k0 + 32 + kh * 16);
                        ns0 = pS[0]; ns1 = pS[1]; nt0 = pT[0]; nt1 = pT[1];
                    }
                    // next step's seg0 bfr -> regs across the barrier
#pragma unroll
                    for (int ct = 0; ct < 5; ct++) {
                        int col = w * 80 + ct * 16 + ln;
                        bfr0[ct] = *(const bf16x8*)(WT + (size_t)col * K3 +
                                                    k0 + 32 + q * 8);
                    }
                }
                __builtin_amdgcn_sched_barrier(0);
            }
            __builtin_amdgcn_s_setprio(1);
#pragma unroll
            for (int rt = 0; rt < 8; rt++) {
                bf16x8 af = *(const bf16x8*)&bufC[sidx32(seg, rt, lane)];
#pragma unroll
                for (int ct = 0; ct < 5; ct++)
                    acc[ct][rt] = __builtin_amdgcn_mfma_f32_16x16x32_bf16(
                        af, bfr[ct], acc[ct][rt], 0, 0, 0);
            }
            __builtin_amdgcn_s_setprio(0);
        }
        if constexpr (BF) {
            if (pf) writeStage(bufN, rtw, lnw, kcb, ns0, ns1, nt0, nt1);
        } else {
            if (pf) stage_f32(beliefs + srow + k0 + 32 + kh * 16,
                              beliefs + trow + k0 + 32 + kh * 16,
                              bufN, rtw, lnw, kcb);
        }
        __syncthreads();
    }

    // ---- epilogue: two 64-row halves; h2 lives in acts cols 0..63 ----
#pragma unroll
    for (int h = 0; h < 2; h++) {
        // phase B: bias + relu -> acts[64][320]. C/D: col=lane&15, row=q*4+reg.
#pragma unroll
        for (int ct = 0; ct < 5; ct++) {
            int col = w * 80 + ct * 16 + ln;
            float bias = (col < 128) ? pb1[col]
                       : (col < 192) ? db1[col - 128]
                                     : rb1[col - 192];
#pragma unroll
            for (int rt4 = 0; rt4 < 4; rt4++)
#pragma unroll
                for (int i = 0; i < 4; i++) {
                    int lrow = rt4 * 16 + q * 4 + i;
                    float v = acc[ct][h * 4 + rt4][i] + bias;
                    acts[lrow][col] = f2b(fmaxf(v, 0.f));
                }
        }
        __syncthreads();

        // C1: relations = relu1_r[64x128] @ rw2 + rb2 (reads acts 192..319)
        {
            f32x4 rc[4];
#pragma unroll
            for (int rt = 0; rt < 4; rt++) rc[rt] = (f32x4)(0.f);
#pragma unroll
            for (int ks = 0; ks < 4; ks++) {
                bf16x8 bfr = *(const bf16x8*)(rw2T + (w * 16 + ln) * 128 +
                                              ks * 32 + q * 8);
#pragma unroll
                for (int rt = 0; rt < 4; rt++) {
                    bf16x8 afr = *(const bf16x8*)&acts[rt * 16 + ln][192 + ks * 32 + q * 8];
                    rc[rt] = __builtin_amdgcn_mfma_f32_16x16x32_bf16(afr, bfr, rc[rt], 0, 0, 0);
                }
            }
            int col = w * 16 + ln;
            float bias = rb2[col];
            float* rel = out + 2 * (size_t)N;
#pragma unroll
            for (int rt = 0; rt < 4; rt++)
#pragma unroll
                for (int i = 0; i < 4; i++) {
                    int grow = r0 + h * 64 + rt * 16 + q * 4 + i;
                    rel[(size_t)grow * 64 + col] = rc[rt][i] + bias;
                }
        }

        // C2: pc = relu1_p[64x128] @ pw2 (reads acts 0..127) -> regs
        f32x4 pc[4];
        {
#pragma unroll
            for (int rt = 0; rt < 4; rt++) pc[rt] = (f32x4)(0.f);
#pragma unroll
            for (int ks = 0; ks < 4; ks++) {
                bf16x8 bfr = *(const bf16x8*)(pw2T + (w * 16 + ln) * 128 +
                                              ks * 32 + q * 8);
#pragma unroll
                for (int rt = 0; rt < 4; rt++) {
                    bf16x8 afr = *(const bf16x8*)&acts[rt * 16 + ln][0 + ks * 32 + q * 8];
                    pc[rt] = __builtin_amdgcn_mfma_f32_16x16x32_bf16(afr, bfr, pc[rt], 0, 0, 0);
                }
            }
        }
        __syncthreads();   // all C2 reads of acts cols 0..127 complete

        // write h2 = relu(pc + pb2) into acts cols 0..63 (now dead)
        {
            int col = w * 16 + ln;
            float bias = pb2[col];
#pragma unroll
            for (int rt = 0; rt < 4; rt++)
#pragma unroll
                for (int i = 0; i < 4; i++) {
                    int lrow = rt * 16 + q * 4 + i;
                    acts[lrow][col] = f2b(fmaxf(pc[rt][i] + bias, 0.f));
                }
        }
        __syncthreads();   // h2 visible

        // C3: probs (reads acts[t][0..63]); C4: directions (acts[.][128..191])
        if (t < 64) {
            float s = pb3[0];
#pragma unroll 8
            for (int k = 0; k < 64; k++) s += b2f(acts[t][k]) * pw3[k];
            float pr = 1.f / (1.f + __expf(-s));
            out[r0 + h * 64 + t] = pr;
        } else if (t < 128) {
            int lrow = t - 64;
            float s = db2[0];
#pragma unroll 8
            for (int k = 0; k < 64; k++) s += b2f(acts[lrow][128 + k]) * dw2[k];
            float dir = (1.f / (1.f + __expf(-s))) * 1.57079632679489662f;
            out[(size_t)N + r0 + h * 64 + lrow] = dir;
        }
        __syncthreads();   // protect acts before next half overwrites
    }
}

extern "C" void kernel_launch(void* const* d_in, const int* in_sizes, int n_in,
                              void* d_out, int out_size, void* d_ws, size_t ws_size,
                              hipStream_t stream) {
    const float* beliefs = (const float*)d_in[0];
    const int* src = (const int*)d_in[1];
    const int* tgt = (const int*)d_in[2];
    const float* pw1 = (const float*)d_in[3];
    const float* pb1 = (const float*)d_in[4];
    const float* pw2 = (const float*)d_in[5];
    const float* pb2 = (const float*)d_in[6];
    const float* pw3 = (const float*)d_in[7];
    const float* pb3 = (const float*)d_in[8];
    const float* dw1 = (const float*)d_in[9];
    const float* db1 = (const float*)d_in[10];
    const float* dw2 = (const float*)d_in[11];
    const float* db2 = (const float*)d_in[12];
    const float* rw1 = (const float*)d_in[13];
    const float* rb1 = (const float*)d_in[14];
    const float* rw2 = (const float*)d_in[15];
    const float* rb2 = (const float*)d_in[16];

    short* ws = (short*)d_ws;
    short* WT    = ws;
    short* pw2T  = ws + P2T_OFF;
    short* rw2T  = ws + R2T_OFF;
    short* bel16 = ws + BEL_OFF;
    const int N = in_sizes[1];

    const bool useBf = ws_size >= (size_t)(PREP_TOT + BEL_ELEMS) * sizeof(short);
    const int prepElems = useBf ? (PREP_TOT + BEL_ELEMS) : PREP_TOT;
    const int prep8 = prepElems / 8;

    prep_kernel<<<(prep8 + 255) / 256, 256, 0, stream>>>(
        pw1, dw1, rw1, pw2, rw2, beliefs, ws, prep8);

    if (useBf)
        edge_main<true><<<N / ROWS, 256, 0, stream>>>(
            beliefs, bel16, src, tgt, pb1, db1, rb1, pb2, pw3, pb3,
            dw2, db2, rb2, WT, pw2T, rw2T, (float*)d_out, N);
    else
        edge_main<false><<<N / ROWS, 256, 0, stream>>>(
            beliefs, bel16, src, tgt, pb1, db1, rb1, pb2, pw3, pb3,
            dw2, db2, rb2, WT, pw2T, rw2T, (float*)d_out, N);
}